// Round 16
// baseline (1023.360 us; speedup 1.0000x reference)
//
#include <hip/hip_runtime.h>

// ConvLSTM2D x2, 4-step temporal blocking, 5 launches, FULLY STATIC waves.
// IDENTICAL to R11 except __launch_bounds__(1024, 1): R11's (1024,4) budgeted
// 64 VGPR/wave -> all accumulators spilled to scratch (450 MB/dispatch, its
// entire 241us). LDS=144KB already caps at 1 block/CU, so only the register
// budget changes. Launch j: L1 t=4j..4j+3 (j=0..3); L2 t=4j-4..4j-1 (j=1..4).

typedef __bf16 bf16x8 __attribute__((ext_vector_type(8)));
typedef float f32x4 __attribute__((ext_vector_type(4)));

#define WPK_ELEMS 73728   // per layer: 18 kchunks * 8 ntiles * 64 lanes * 8
#define PLANE 524288      // 4*64*64*32 elems per plane

__device__ __forceinline__ float fsigmoid(float z) {
    return 1.0f / (1.0f + __expf(-z));
}
__device__ __forceinline__ float ftanh(float z) {
    z = fminf(15.0f, fmaxf(-15.0f, z));
    float e = __expf(2.0f * z);
    return (e - 1.0f) / (e + 1.0f);
}

__global__ __launch_bounds__(256) void pack_weights(
    const float* __restrict__ wk1, const float* __restrict__ wr1,
    const float* __restrict__ wk2, const float* __restrict__ wr2,
    __bf16* __restrict__ wpk)
{
    int i = blockIdx.x * 256 + threadIdx.x;
    if (i >= 2 * WPK_ELEMS) return;
    int layer = i / WPK_ELEMS;
    int r = i - layer * WPK_ELEMS;
    int j2 = r & 7;
    int L  = (r >> 3) & 63;
    int nt = (r >> 9) & 7;
    int cix = r >> 12;
    int tap = cix >> 1, src = cix & 1;
    int s = ((L >> 4) << 3) + j2;
    int gate = nt & 3;
    int f = ((nt >> 2) << 4) + (L & 15);
    int n = (gate << 5) + f;
    const float* w = layer ? (src ? wr2 : wk2) : (src ? wr1 : wk1);
    wpk[i] = (__bf16)w[(tap * 32 + s) * 128 + n];
}

__device__ __forceinline__ bf16x8 cvt8(const float* p) {
    const float4 f0 = *(const float4*)p;
    const float4 f1 = *(const float4*)(p + 4);
    bf16x8 v;
    v[0] = (__bf16)f0.x; v[1] = (__bf16)f0.y;
    v[2] = (__bf16)f0.z; v[3] = (__bf16)f0.w;
    v[4] = (__bf16)f1.x; v[5] = (__bf16)f1.y;
    v[6] = (__bf16)f1.z; v[7] = (__bf16)f1.w;
    return v;
}

#define MFMA8(A0, A1, WP)                                                                 \
    acc[0][0] = __builtin_amdgcn_mfma_f32_16x16x32_bf16(A0, WP[0],   acc[0][0], 0, 0, 0); \
    acc[0][1] = __builtin_amdgcn_mfma_f32_16x16x32_bf16(A0, WP[64],  acc[0][1], 0, 0, 0); \
    acc[0][2] = __builtin_amdgcn_mfma_f32_16x16x32_bf16(A0, WP[128], acc[0][2], 0, 0, 0); \
    acc[0][3] = __builtin_amdgcn_mfma_f32_16x16x32_bf16(A0, WP[192], acc[0][3], 0, 0, 0); \
    acc[1][0] = __builtin_amdgcn_mfma_f32_16x16x32_bf16(A1, WP[0],   acc[1][0], 0, 0, 0); \
    acc[1][1] = __builtin_amdgcn_mfma_f32_16x16x32_bf16(A1, WP[64],  acc[1][1], 0, 0, 0); \
    acc[1][2] = __builtin_amdgcn_mfma_f32_16x16x32_bf16(A1, WP[128], acc[1][2], 0, 0, 0); \
    acc[1][3] = __builtin_amdgcn_mfma_f32_16x16x32_bf16(A1, WP[192], acc[1][3], 0, 0, 0);

__global__ __launch_bounds__(1024, 1) void clstm_s4(
    const float* __restrict__ x,
    const __bf16* __restrict__ wpk1, const __bf16* __restrict__ wpk2,
    const float* __restrict__ bias1, const float* __restrict__ bias2,
    __bf16* __restrict__ h1buf,       // 8 planes, t%8
    __bf16* __restrict__ h2buf,       // 2 parity planes (by launch j)
    float* __restrict__ c1,           // 2 parity planes (by launch j)
    float* __restrict__ c2,
    float* __restrict__ out, int j)
{
    __shared__ __bf16 xbuf[10 * 66 * 36];   // input-conv src window (restaged/step)
    __shared__ __bf16 hbuf[10 * 66 * 36];   // h window, in-place across steps
    __shared__ float  cbuf[6 * 64 * 32];    // c window rows rw2..7

    const int blk = blockIdx.x;
    const int xcd = blk & 7;
    const int rest = blk >> 3;
    const int layer = rest >> 4;
    if (layer ? (j < 1) : (j > 3)) return;
    const int grp = xcd * 16 + (rest & 15);  // XCD-contiguous rows
    const int T0 = layer ? 4 * (j - 1) : 4 * j;
    const int R = grp << 1;
    const int b = R >> 6, y0 = R & 63;
    const bool firstT = (T0 == 0);

    const int tid = threadIdx.x;
    const int wid = tid >> 6, L = tid & 63;
    const int c = L & 15, q = L >> 4, q8 = q * 8;
    const int row = wid >> 1;                // 0..7; window row rw=row+1
    const int fh = wid & 1;
    const int f = fh * 16 + c;
    const int yy = y0 - 3 + row;
    const bool rv = ((unsigned)yy < 64u);
    const bool own = (row == 3 || row == 4); // yy = y0 or y0+1 (always in range)
    const int crow = row - 1;                // cbuf row for rw2..7
    const bool cbv = ((unsigned)crow < 6u);

    const bf16x8* wpkv = (const bf16x8*)(layer ? wpk2 : wpk1);
    const float* bias = layer ? bias2 : bias1;
    float bv[4];
    #pragma unroll
    for (int g = 0; g < 4; ++g) bv[g] = bias[g * 32 + f];

    const float* cglob = (layer ? c2 : c1) + (size_t)((j - 1) & 1) * PLANE;
    float* cw = (layer ? c2 : c1) + (size_t)(j & 1) * PLANE;
    __bf16* h2w = h2buf + (size_t)(j & 1) * PLANE;
    const size_t gbase = ((size_t)(b * 64 + (rv ? yy : 0)) * 64) * 32;

    for (int s = 0; s < 4; ++s) {
        const int t = T0 + s;

        // ---- stage xbuf rows y0-4..y0+5 from x@t (L1) or h1@t (L2) ----
        {
            const float*  xs = x + (size_t)(b * 16 + t) * 131072;
            const __bf16* hs = h1buf + (size_t)(t & 7) * PLANE;
            for (int i = tid; i < 2640; i += 1024) {
                const int g = i & 3, rc2 = i >> 2;
                const int cc = rc2 % 66, rw = rc2 / 66;
                const int yr = y0 - 4 + rw, xc = cc - 1;
                bf16x8 v = {};
                if ((unsigned)yr < 64u && (unsigned)xc < 64u) {
                    if (layer) v = *(const bf16x8*)(hs + (((size_t)(b * 64 + yr)) * 64 + xc) * 32 + g * 8);
                    else       v = cvt8(xs + (((size_t)yr * 64 + xc) * 32 + g * 8));
                }
                *(bf16x8*)(xbuf + (rw * 66 + cc) * 36 + g * 8) = v;
            }
        }
        // ---- s=0: stage hbuf (h@T0-1) or zero it ----
        if (s == 0) {
            if (!firstT) {
                const __bf16* rs = layer ? (h2buf + (size_t)((j - 1) & 1) * PLANE)
                                         : (h1buf + (size_t)((T0 - 1) & 7) * PLANE);
                for (int i = tid; i < 2640; i += 1024) {
                    const int g = i & 3, rc2 = i >> 2;
                    const int cc = rc2 % 66, rw = rc2 / 66;
                    const int yr = y0 - 4 + rw, xc = cc - 1;
                    bf16x8 v = {};
                    if ((unsigned)yr < 64u && (unsigned)xc < 64u)
                        v = *(const bf16x8*)(rs + (((size_t)(b * 64 + yr)) * 64 + xc) * 32 + g * 8);
                    *(bf16x8*)(hbuf + (rw * 66 + cc) * 36 + g * 8) = v;
                }
            } else {
                for (int i = tid; i < 2970; i += 1024)
                    *(bf16x8*)(hbuf + i * 8) = (bf16x8){};
            }
        }
        __syncthreads();

        // ---- compute + epilogue (reads xbuf/hbuf; h@t kept in regs) ----
        float hv[2][2][4];
        if (rv) {
            #pragma unroll
            for (int mp = 0; mp < 2; ++mp) {
                f32x4 acc[2][4];
                #pragma unroll
                for (int m2 = 0; m2 < 2; ++m2)
                    #pragma unroll
                    for (int g = 0; g < 4; ++g)
                        acc[m2][g] = (f32x4){bv[g], bv[g], bv[g], bv[g]};

                #pragma unroll
                for (int tap = 0; tap < 9; ++tap) {
                    const int dyk = tap / 3, dxk = tap - dyk * 3;
                    const int bx = ((row + dyk) * 66 + mp * 32 + c + dxk) * 36 + q8;
                    const bf16x8 a0 = *(const bf16x8*)(xbuf + bx);
                    const bf16x8 a1 = *(const bf16x8*)(xbuf + bx + 576);
                    const bf16x8* wpx = wpkv + (size_t)((tap * 2) * 8 + fh * 4) * 64 + L;
                    MFMA8(a0, a1, wpx);
                    const bf16x8 h0 = *(const bf16x8*)(hbuf + bx);
                    const bf16x8 h1v = *(const bf16x8*)(hbuf + bx + 576);
                    const bf16x8* wph = wpkv + (size_t)((tap * 2 + 1) * 8 + fh * 4) * 64 + L;
                    MFMA8(h0, h1v, wph);
                }

                #pragma unroll
                for (int m2 = 0; m2 < 2; ++m2) {
                    #pragma unroll
                    for (int r = 0; r < 4; ++r) {
                        const int px = mp * 32 + m2 * 16 + q * 4 + r;
                        const float ig = fsigmoid(acc[m2][0][r]);
                        const float fg = fsigmoid(acc[m2][1][r]);
                        const float gg = ftanh(acc[m2][2][r]);
                        const float og = fsigmoid(acc[m2][3][r]);
                        const size_t gidx = gbase + (size_t)px * 32 + f;
                        float cold;
                        if (s == 0) cold = firstT ? 0.f : cglob[gidx];
                        else        cold = cbv ? cbuf[(crow * 64 + px) * 32 + f] : 0.f;
                        const float cn = fg * cold + ig * gg;
                        if (cbv) cbuf[(crow * 64 + px) * 32 + f] = cn;
                        const float h_ = og * ftanh(cn);
                        hv[mp][m2][r] = h_;
                        if (own) {
                            if (layer) {
                                out[((size_t)(b * 16 + t) * 4096 + (size_t)yy * 64 + px) * 32 + f] = h_;
                                if (s == 3) { h2w[gidx] = (__bf16)h_; cw[gidx] = cn; }
                            } else {
                                h1buf[(size_t)(t & 7) * PLANE + gidx] = (__bf16)h_;
                                if (s == 3) cw[gidx] = cn;
                            }
                        }
                    }
                }
            }
        }
        __syncthreads();

        // ---- publish h@t into hbuf (in place) for next step ----
        if (s < 3 && rv) {
            #pragma unroll
            for (int mp = 0; mp < 2; ++mp)
                #pragma unroll
                for (int m2 = 0; m2 < 2; ++m2)
                    #pragma unroll
                    for (int r = 0; r < 4; ++r) {
                        const int px = mp * 32 + m2 * 16 + q * 4 + r;
                        hbuf[((row + 1) * 66 + px + 1) * 36 + f] = (__bf16)hv[mp][m2][r];
                    }
        }
    }
}

extern "C" void kernel_launch(void* const* d_in, const int* in_sizes, int n_in,
                              void* d_out, int out_size, void* d_ws, size_t ws_size,
                              hipStream_t stream)
{
    const float* x   = (const float*)d_in[0];
    const float* k1  = (const float*)d_in[1];
    const float* rk1 = (const float*)d_in[2];
    const float* b1  = (const float*)d_in[3];
    const float* k2  = (const float*)d_in[4];
    const float* rk2 = (const float*)d_in[5];
    const float* b2  = (const float*)d_in[6];
    float* out = (float*)d_out;

    __bf16* wpk1  = (__bf16*)d_ws;
    __bf16* wpk2  = wpk1 + WPK_ELEMS;
    __bf16* h1buf = wpk2 + WPK_ELEMS;                     // 8 planes bf16
    __bf16* h2buf = h1buf + 8 * (size_t)PLANE;            // 2 planes bf16
    float*  c1    = (float*)(h2buf + 2 * (size_t)PLANE);  // 2 planes fp32
    float*  c2    = c1 + 2 * (size_t)PLANE;

    pack_weights<<<(2 * WPK_ELEMS + 255) / 256, 256, 0, stream>>>(k1, rk1, k2, rk2, wpk1);

    for (int j = 0; j <= 4; ++j) {
        clstm_s4<<<256, 1024, 0, stream>>>(
            x, wpk1, wpk2, b1, b2, h1buf, h2buf, c1, c2, out, j);
    }
}

// Round 17
// 229.988 us; speedup vs baseline: 4.4496x; 4.4496x over previous
//
#include <hip/hip_runtime.h>

// ConvLSTM2D x2, 2-step temporal blocking, 9 launches (R15 base, 245us),
// restructured for staging/compute overlap. 256 blocks x 1024 thr.
//   P1: stage tXA + tXB (16 waves)
//   P2: waves 0-7 step-A x-side | waves 8-11 step-B x-side |
//       waves 12-15 stage tRA + zero tHA (hidden under compute)
//   P3: waves 0-7 step-A h-side + epilogue A (tHA/cpass/global)
//   P4: waves 8-11 step-B h-side + epilogue B
// ONE unified accU[4][4] per thread (step-A acc for waves 0-7, step-B acc for
// waves 8-11) -> 64 accum regs under the 128-reg cap of 1024-thr blocks.
// (R16 lesson: 1024-thr blocks pin 4 waves/SIMD -> 128 unified regs/wave max,
// independent of __launch_bounds__.)

typedef __bf16 bf16x8 __attribute__((ext_vector_type(8)));
typedef float f32x4 __attribute__((ext_vector_type(4)));

#define WPK_ELEMS 73728   // per layer: 18 kchunks * 8 ntiles * 64 lanes * 8
#define PLANE 524288      // 4*64*64*32 elems per plane

__device__ __forceinline__ float fsigmoid(float z) {
    return 1.0f / (1.0f + __expf(-z));
}
__device__ __forceinline__ float ftanh(float z) {
    z = fminf(15.0f, fmaxf(-15.0f, z));
    float e = __expf(2.0f * z);
    return (e - 1.0f) / (e + 1.0f);
}

__global__ __launch_bounds__(256) void pack_weights(
    const float* __restrict__ wk1, const float* __restrict__ wr1,
    const float* __restrict__ wk2, const float* __restrict__ wr2,
    __bf16* __restrict__ wpk)
{
    int i = blockIdx.x * 256 + threadIdx.x;
    if (i >= 2 * WPK_ELEMS) return;
    int layer = i / WPK_ELEMS;
    int r = i - layer * WPK_ELEMS;
    int j2 = r & 7;
    int L  = (r >> 3) & 63;
    int nt = (r >> 9) & 7;
    int cix = r >> 12;            // tap*2 + src
    int tap = cix >> 1, src = cix & 1;
    int s = ((L >> 4) << 3) + j2;
    int gate = nt & 3;
    int f = ((nt >> 2) << 4) + (L & 15);
    int n = (gate << 5) + f;
    const float* w = layer ? (src ? wr2 : wk2) : (src ? wr1 : wk1);
    wpk[i] = (__bf16)w[(tap * 32 + s) * 128 + n];
}

__device__ __forceinline__ bf16x8 cvt8(const float* p) {
    const float4 f0 = *(const float4*)p;
    const float4 f1 = *(const float4*)(p + 4);
    bf16x8 v;
    v[0] = (__bf16)f0.x; v[1] = (__bf16)f0.y;
    v[2] = (__bf16)f0.z; v[3] = (__bf16)f0.w;
    v[4] = (__bf16)f1.x; v[5] = (__bf16)f1.y;
    v[6] = (__bf16)f1.z; v[7] = (__bf16)f1.w;
    return v;
}

// 16 MFMAs: 4 A-tiles (M=64) x 4 gates, sharing one 4-fragment B load.
#define MFMA16(A0, A1, A2, A3, WP, ACC)                                                   \
    {                                                                                     \
        const bf16x8 w0 = WP[0], w1 = WP[64], w2 = WP[128], w3 = WP[192];                 \
        ACC[0][0] = __builtin_amdgcn_mfma_f32_16x16x32_bf16(A0, w0, ACC[0][0], 0, 0, 0);  \
        ACC[0][1] = __builtin_amdgcn_mfma_f32_16x16x32_bf16(A0, w1, ACC[0][1], 0, 0, 0);  \
        ACC[0][2] = __builtin_amdgcn_mfma_f32_16x16x32_bf16(A0, w2, ACC[0][2], 0, 0, 0);  \
        ACC[0][3] = __builtin_amdgcn_mfma_f32_16x16x32_bf16(A0, w3, ACC[0][3], 0, 0, 0);  \
        ACC[1][0] = __builtin_amdgcn_mfma_f32_16x16x32_bf16(A1, w0, ACC[1][0], 0, 0, 0);  \
        ACC[1][1] = __builtin_amdgcn_mfma_f32_16x16x32_bf16(A1, w1, ACC[1][1], 0, 0, 0);  \
        ACC[1][2] = __builtin_amdgcn_mfma_f32_16x16x32_bf16(A1, w2, ACC[1][2], 0, 0, 0);  \
        ACC[1][3] = __builtin_amdgcn_mfma_f32_16x16x32_bf16(A1, w3, ACC[1][3], 0, 0, 0);  \
        ACC[2][0] = __builtin_amdgcn_mfma_f32_16x16x32_bf16(A2, w0, ACC[2][0], 0, 0, 0);  \
        ACC[2][1] = __builtin_amdgcn_mfma_f32_16x16x32_bf16(A2, w1, ACC[2][1], 0, 0, 0);  \
        ACC[2][2] = __builtin_amdgcn_mfma_f32_16x16x32_bf16(A2, w2, ACC[2][2], 0, 0, 0);  \
        ACC[2][3] = __builtin_amdgcn_mfma_f32_16x16x32_bf16(A2, w3, ACC[2][3], 0, 0, 0);  \
        ACC[3][0] = __builtin_amdgcn_mfma_f32_16x16x32_bf16(A3, w0, ACC[3][0], 0, 0, 0);  \
        ACC[3][1] = __builtin_amdgcn_mfma_f32_16x16x32_bf16(A3, w1, ACC[3][1], 0, 0, 0);  \
        ACC[3][2] = __builtin_amdgcn_mfma_f32_16x16x32_bf16(A3, w2, ACC[3][2], 0, 0, 0);  \
        ACC[3][3] = __builtin_amdgcn_mfma_f32_16x16x32_bf16(A3, w3, ACC[3][3], 0, 0, 0);  \
    }

__global__ __launch_bounds__(1024, 1) void clstm_v17(
    const float* __restrict__ x,
    const __bf16* __restrict__ wpk1, const __bf16* __restrict__ wpk2,
    const float* __restrict__ bias1, const float* __restrict__ bias2,
    __bf16* __restrict__ h1buf,       // 4 planes, t%4
    __bf16* __restrict__ h2buf,       // 2 parity planes (odd t)
    float* __restrict__ c1,           // 2 parity planes (odd t)
    float* __restrict__ c2,
    float* __restrict__ out, int j)
{
    __shared__ __bf16 tXA[6 * 66 * 36];   // step-A input src rows y0-2..y0+3
    __shared__ __bf16 tRA[6 * 66 * 36];   // step-A recurrent src (h@T0-1)
    __shared__ __bf16 tXB[4 * 66 * 36];   // step-B input src rows y0-1..y0+2
    __shared__ __bf16 tHA[4 * 66 * 36];   // h@T0 rows y0-1..y0+2 (zero borders)
    __shared__ float  cpass[2 * 64 * 32]; // c@T0, own rows

    const int blk = blockIdx.x;
    const int k = blk >> 3;
    const int layer = k >> 4;
    if (layer ? (j < 1) : (j > 7)) return;
    const int grp = (blk & 7) * 16 + (k & 15);   // XCD-contiguous rows
    const int T0 = layer ? (2 * j - 2) : (2 * j);
    const int R = grp << 1;
    const int b = R >> 6, y0 = R & 63;

    const int tid = threadIdx.x;
    const int wid = tid >> 6, L = tid & 63;
    const int c = L & 15, q = L >> 4, q8 = q * 8;
    const int fh = wid & 1;               // valid for waves 0-11
    const int f = fh * 16 + c;
    const int wr = wid >> 1;              // waves 0-7: window row 0..3
    const int o  = wr - 4;                // waves 8-11: own row 0..1

    const bf16x8* wpkv = (const bf16x8*)(layer ? wpk2 : wpk1);
    const float* bias = layer ? bias2 : bias1;
    float* cl = layer ? c2 : c1;

    const float*  xA  = x + (size_t)(b * 16 + T0) * 131072;
    const float*  xB  = xA + 131072;
    const __bf16* h1A = h1buf + (size_t)(T0 & 3) * PLANE;
    const __bf16* h1B = h1buf + (size_t)((T0 + 1) & 3) * PLANE;
    const __bf16* hRA = layer ? (h2buf + (size_t)(((T0 - 1) >> 1) & 1) * PLANE)
                              : (h1buf + (size_t)((T0 - 1) & 3) * PLANE);

    // ================= P1: stage tXA + tXB ==================================
    for (int i = tid; i < 2640; i += 1024) {
        const int tb = (i >= 1584);
        const int r2 = tb ? (i - 1584) : i;
        const int g = r2 & 3;
        const int rc = r2 >> 2;
        const int cc = rc % 66;
        const int row = rc / 66;
        const int yy = (tb ? y0 - 1 : y0 - 2) + row;
        const int xc = cc - 1;
        bf16x8 v = {};
        if ((unsigned)yy < 64u && (unsigned)xc < 64u) {
            if (!layer) {
                v = cvt8((tb ? xB : xA) + ((size_t)yy * 64 + xc) * 32 + g * 8);
            } else {
                const __bf16* s = tb ? h1B : h1A;
                v = *(const bf16x8*)(s + (((size_t)(b * 64 + yy)) * 64 + xc) * 32 + g * 8);
            }
        }
        *(bf16x8*)((tb ? tXB : tXA) + (row * 66 + cc) * 36 + g * 8) = v;
    }
    __syncthreads();

    // ================= P2: x-side compute || tRA staging + tHA zero =========
    f32x4 accU[4][4];   // waves 0-7: step-A acc; waves 8-11: step-B acc

    if (wid < 8) {
        const int ra = y0 - 1 + wr;
        if ((unsigned)ra < 64u) {
            float bv[4];
            #pragma unroll
            for (int g = 0; g < 4; ++g) bv[g] = bias[g * 32 + f];
            #pragma unroll
            for (int m = 0; m < 4; ++m)
                #pragma unroll
                for (int g = 0; g < 4; ++g)
                    accU[m][g] = (f32x4){bv[g], bv[g], bv[g], bv[g]};

            #pragma unroll
            for (int tap = 0; tap < 9; ++tap) {
                const int dyk = tap / 3, dxk = tap - dyk * 3;
                const int lb = ((wr + dyk) * 66 + c + dxk) * 36 + q8;
                const bf16x8 a0 = *(const bf16x8*)(tXA + lb);
                const bf16x8 a1 = *(const bf16x8*)(tXA + lb + 16 * 36);
                const bf16x8 a2 = *(const bf16x8*)(tXA + lb + 32 * 36);
                const bf16x8 a3 = *(const bf16x8*)(tXA + lb + 48 * 36);
                const bf16x8* wp = wpkv + (size_t)((tap * 2) * 8 + fh * 4) * 64 + L;
                MFMA16(a0, a1, a2, a3, wp, accU);
            }
        }
    } else if (wid < 12) {
        float bv[4];
        #pragma unroll
        for (int g = 0; g < 4; ++g) bv[g] = bias[g * 32 + f];
        #pragma unroll
        for (int m = 0; m < 4; ++m)
            #pragma unroll
            for (int g = 0; g < 4; ++g)
                accU[m][g] = (f32x4){bv[g], bv[g], bv[g], bv[g]};

        #pragma unroll
        for (int tap = 0; tap < 9; ++tap) {
            const int dyk = tap / 3, dxk = tap - dyk * 3;
            const int lb = ((o + dyk) * 66 + c + dxk) * 36 + q8;
            const bf16x8 a0 = *(const bf16x8*)(tXB + lb);
            const bf16x8 a1 = *(const bf16x8*)(tXB + lb + 16 * 36);
            const bf16x8 a2 = *(const bf16x8*)(tXB + lb + 32 * 36);
            const bf16x8 a3 = *(const bf16x8*)(tXB + lb + 48 * 36);
            const bf16x8* wp = wpkv + (size_t)((tap * 2) * 8 + fh * 4) * 64 + L;
            MFMA16(a0, a1, a2, a3, wp, accU);
        }
    } else {
        const int t2 = tid - 768;             // 0..255
        if (T0 > 0) {
            for (int i = t2; i < 1584; i += 256) {
                const int g = i & 3;
                const int rc = i >> 2;
                const int cc = rc % 66;
                const int row = rc / 66;
                const int yy = y0 - 2 + row;
                const int xc = cc - 1;
                bf16x8 v = {};
                if ((unsigned)yy < 64u && (unsigned)xc < 64u)
                    v = *(const bf16x8*)(hRA + (((size_t)(b * 64 + yy)) * 64 + xc) * 32 + g * 8);
                *(bf16x8*)(tRA + (row * 66 + cc) * 36 + g * 8) = v;
            }
        }
        for (int i = t2; i < 1188; i += 256)
            *(bf16x8*)(tHA + i * 8) = (bf16x8){};
    }
    __syncthreads();

    // ================= P3: step-A h-side + epilogue A (waves 0-7) ===========
    if (wid < 8) {
        const int ra = y0 - 1 + wr;
        const bool rv = ((unsigned)ra < 64u);
        if (rv) {
            if (T0 > 0) {
                #pragma unroll
                for (int tap = 0; tap < 9; ++tap) {
                    const int dyk = tap / 3, dxk = tap - dyk * 3;
                    const int lb = ((wr + dyk) * 66 + c + dxk) * 36 + q8;
                    const bf16x8 h0 = *(const bf16x8*)(tRA + lb);
                    const bf16x8 h1v = *(const bf16x8*)(tRA + lb + 16 * 36);
                    const bf16x8 h2v = *(const bf16x8*)(tRA + lb + 32 * 36);
                    const bf16x8 h3v = *(const bf16x8*)(tRA + lb + 48 * 36);
                    const bf16x8* wp = wpkv + (size_t)((tap * 2 + 1) * 8 + fh * 4) * 64 + L;
                    MFMA16(h0, h1v, h2v, h3v, wp, accU);
                }
            }
            const bool own = (wr == 1 || wr == 2);
            const float* crd = cl + (size_t)((j - 1) & 1) * PLANE;
            const size_t rowA = (size_t)(b * 64 + ra) * 2048;
            #pragma unroll
            for (int m = 0; m < 4; ++m) {
                #pragma unroll
                for (int r = 0; r < 4; ++r) {
                    const int px = m * 16 + q * 4 + r;
                    const float ig = fsigmoid(accU[m][0][r]);
                    const float fg = fsigmoid(accU[m][1][r]);
                    const float gg = ftanh(accU[m][2][r]);
                    const float og = fsigmoid(accU[m][3][r]);
                    const float cold = T0 ? crd[rowA + (size_t)px * 32 + f] : 0.0f;
                    const float cn = (T0 ? fg * cold : 0.0f) + ig * gg;
                    const float hv = og * ftanh(cn);
                    tHA[(wr * 66 + px + 1) * 36 + f] = (__bf16)hv;
                    if (own) {
                        cpass[(wr - 1) * 2048 + px * 32 + f] = cn;
                        if (layer)
                            out[((size_t)(b * 16 + T0) * 4096 + (size_t)ra * 64 + px) * 32 + f] = hv;
                        else
                            h1buf[(size_t)(T0 & 3) * PLANE + rowA + (size_t)px * 32 + f] = (__bf16)hv;
                    }
                }
            }
        }
    }
    __syncthreads();

    // ================= P4: step-B h-side + epilogue B (waves 8-11) ==========
    if (wid >= 8 && wid < 12) {
        #pragma unroll
        for (int tap = 0; tap < 9; ++tap) {
            const int dyk = tap / 3, dxk = tap - dyk * 3;
            const int lb = ((o + dyk) * 66 + c + dxk) * 36 + q8;
            const bf16x8 h0 = *(const bf16x8*)(tHA + lb);
            const bf16x8 h1v = *(const bf16x8*)(tHA + lb + 16 * 36);
            const bf16x8 h2v = *(const bf16x8*)(tHA + lb + 32 * 36);
            const bf16x8 h3v = *(const bf16x8*)(tHA + lb + 48 * 36);
            const bf16x8* wp = wpkv + (size_t)((tap * 2 + 1) * 8 + fh * 4) * 64 + L;
            MFMA16(h0, h1v, h2v, h3v, wp, accU);
        }
        const int rb = y0 + o;
        float* cwr = cl + (size_t)(j & 1) * PLANE;
        __bf16* h2w = h2buf + (size_t)(((T0 + 1) >> 1) & 1) * PLANE;
        const size_t rowB = (size_t)(b * 64 + rb) * 2048;
        #pragma unroll
        for (int m = 0; m < 4; ++m) {
            #pragma unroll
            for (int r = 0; r < 4; ++r) {
                const int px = m * 16 + q * 4 + r;
                const float ig = fsigmoid(accU[m][0][r]);
                const float fg = fsigmoid(accU[m][1][r]);
                const float gg = ftanh(accU[m][2][r]);
                const float og = fsigmoid(accU[m][3][r]);
                const float cold = cpass[o * 2048 + px * 32 + f];
                const float cn = fg * cold + ig * gg;
                const float hv = og * ftanh(cn);
                cwr[rowB + (size_t)px * 32 + f] = cn;
                if (layer) {
                    out[((size_t)(b * 16 + T0 + 1) * 4096 + (size_t)rb * 64 + px) * 32 + f] = hv;
                    h2w[rowB + (size_t)px * 32 + f] = (__bf16)hv;
                } else {
                    h1buf[(size_t)((T0 + 1) & 3) * PLANE + rowB + (size_t)px * 32 + f] = (__bf16)hv;
                }
            }
        }
    }
}

extern "C" void kernel_launch(void* const* d_in, const int* in_sizes, int n_in,
                              void* d_out, int out_size, void* d_ws, size_t ws_size,
                              hipStream_t stream)
{
    const float* x   = (const float*)d_in[0];
    const float* k1  = (const float*)d_in[1];
    const float* rk1 = (const float*)d_in[2];
    const float* b1  = (const float*)d_in[3];
    const float* k2  = (const float*)d_in[4];
    const float* rk2 = (const float*)d_in[5];
    const float* b2  = (const float*)d_in[6];
    float* out = (float*)d_out;

    __bf16* wpk1  = (__bf16*)d_ws;
    __bf16* wpk2  = wpk1 + WPK_ELEMS;
    __bf16* h1buf = wpk2 + WPK_ELEMS;             // 4 planes bf16
    __bf16* h2buf = h1buf + 4 * (size_t)PLANE;    // 2 planes bf16
    float*  c1    = (float*)(h2buf + 2 * (size_t)PLANE);  // 2 planes fp32
    float*  c2    = c1 + 2 * (size_t)PLANE;

    pack_weights<<<(2 * WPK_ELEMS + 255) / 256, 256, 0, stream>>>(k1, rk1, k2, rk2, wpk1);

    for (int j = 0; j <= 8; ++j) {
        clstm_v17<<<256, 1024, 0, stream>>>(
            x, wpk1, wpk2, b1, b2, h1buf, h2buf, c1, c2, out, j);
    }
}